// Round 8
// baseline (339.004 us; speedup 1.0000x reference)
//
#include <hip/hip_runtime.h>
#include <hip/hip_bf16.h>
#include <stdint.h>

// Problem constants
#define B_   512
#define T_   87
#define C_   512
#define H_   8
#define D_   64
#define BT_  44544        // B_*T_
#define BH_  4096         // B_*H_

typedef __attribute__((ext_vector_type(4))) float f32x4;
typedef __attribute__((ext_vector_type(8))) __bf16 bf16x8;
typedef __attribute__((ext_vector_type(4))) unsigned short u16x4;

__device__ __forceinline__ void gl_lds16(const void* g, void* l) {
  __builtin_amdgcn_global_load_lds(
      (const __attribute__((address_space(1))) unsigned int*)g,
      (__attribute__((address_space(3))) unsigned int*)l, 16, 0, 0);
}

template<int N>
__device__ __forceinline__ void waitv() {
  asm volatile("s_waitcnt vmcnt(%0)" :: "i"(N) : "memory");
}

__device__ __forceinline__ int mod29(int x) {
  return x < 29 ? x : (x < 58 ? x - 29 : x - 58);
}

// ---------------- converts ----------------

__global__ void convert_x_kernel(const float* __restrict__ x,
                                 __hip_bfloat16* __restrict__ xb, int n4) {
  int stride = gridDim.x * blockDim.x;
  for (int i = blockIdx.x * blockDim.x + threadIdx.x; i < n4; i += stride) {
    f32x4 v = ((const f32x4*)x)[i];
    u16x4 o;
    o.x = __builtin_bit_cast(unsigned short, __float2bfloat16(v.x));
    o.y = __builtin_bit_cast(unsigned short, __float2bfloat16(v.y));
    o.z = __builtin_bit_cast(unsigned short, __float2bfloat16(v.z));
    o.w = __builtin_bit_cast(unsigned short, __float2bfloat16(v.w));
    ((u16x4*)xb)[i] = o;
  }
}

__global__ void convert_w_kernel(const float* __restrict__ Wq, const float* __restrict__ Wk,
                                 const float* __restrict__ Wv, const float* __restrict__ Wp,
                                 const float* __restrict__ bq, const float* __restrict__ bk,
                                 const float* __restrict__ bv,
                                 __hip_bfloat16* __restrict__ wqkv,
                                 __hip_bfloat16* __restrict__ wp,
                                 float* __restrict__ biasc) {
  const int NW = 262144;                 // 512*512
  const int total = 3 * NW + NW + 1536;
  int stride = gridDim.x * blockDim.x;
  for (int i = blockIdx.x * blockDim.x + threadIdx.x; i < total; i += stride) {
    if (i < 3 * NW) {
      float v = (i < NW) ? Wq[i] : (i < 2 * NW ? Wk[i - NW] : Wv[i - 2 * NW]);
      wqkv[i] = __float2bfloat16(v);
    } else if (i < 4 * NW) {
      wp[i - 3 * NW] = __float2bfloat16(Wp[i - 3 * NW]);
    } else {
      int j = i - 4 * NW;
      biasc[j] = (j < 512) ? bq[j] : (j < 1024 ? bk[j - 512] : bv[j - 1024]);
    }
  }
}

// zero the pad rows (t = 87..95) of q/k and pad cols of vt
__global__ void zero_pads_kernel(__hip_bfloat16* __restrict__ q_ws,
                                 __hip_bfloat16* __restrict__ k_ws,
                                 __hip_bfloat16* __restrict__ vt_ws) {
  const int per = BH_ * 576;  // 9*64 pad elems per (b,h)
  int stride = gridDim.x * blockDim.x;
  __hip_bfloat16 z = __float2bfloat16(0.f);
  for (int i = blockIdx.x * blockDim.x + threadIdx.x; i < 3 * per; i += stride) {
    if (i < per) {
      int bh = i / 576, rem = i - (i / 576) * 576;
      q_ws[(size_t)bh * 6144 + 5568 + rem] = z;
    } else if (i < 2 * per) {
      int j = i - per;
      int bh = j / 576, rem = j - (j / 576) * 576;
      k_ws[(size_t)bh * 6144 + 5568 + rem] = z;
    } else {
      int j = i - 2 * per;
      int bh = j / 576, rem = j - (j / 576) * 576;
      int d = rem / 9, o = rem - d * 9;
      vt_ws[(size_t)bh * 6144 + d * 96 + 87 + o] = z;
    }
  }
}

// ---------------- 8-phase-style GEMM core (BK=32, 256x256, 8 waves) ----------
// LDS slot (32KB) = A panel [256 rows x 64B] + B panel [256 rows x 64B].
// Rows are 64B (4 x 16B chunks); chunk s of row r holds global chunk
// s ^ ((r>>1)&3)  -> ds_read 2-way bank aliasing only (free, m136).
// Ring of 4 slots = 128KB, stage distance 2 K-tiles, counted vmcnt(4).

// stage one panel (256 x 64B) = 2 gl_lds per thread (512 threads)
__device__ __forceinline__ void stage_panel(const char* g, int kbyte, char* dst,
                                            int wave, int lane) {
  int rl = lane >> 2, s = lane & 3;
#pragma unroll
  for (int j = 0; j < 2; ++j) {
    int rbase = j * 128 + wave * 16;
    int row = rbase + rl;
    int colsw = ((s ^ ((row >> 1) & 3)) << 4);
    gl_lds16(g + (size_t)row * 1024 + kbyte + colsw, dst + rbase * 64);
  }
}

#define PHASE_SEP() __builtin_amdgcn_sched_barrier(0)

// EPI 0: qkv scatter (o0=q,o1=k,o2=vt, bias=biasc). EPI 1: proj fp32 (o0=out).
template<int EPI>
__global__ __launch_bounds__(512, 2) void gemm8_kernel(
    const __hip_bfloat16* __restrict__ A, const __hip_bfloat16* __restrict__ Bt,
    const float* __restrict__ bias, int ntn,
    void* __restrict__ o0, void* __restrict__ o1, void* __restrict__ o2) {
  constexpr int SLOT = 32768;
  constexpr int BOFF = 16384;
  __shared__ __align__(16) char smem[4 * SLOT];

  int tid = threadIdx.x, lane = tid & 63, wave = tid >> 6;
  int r16 = lane & 15, r4 = lane >> 4;

  // bijective XCD swizzle (m204)
  int nwg = gridDim.x;
  int xcd = blockIdx.x & 7, idx = blockIdx.x >> 3;
  int q8 = nwg >> 3, r8 = nwg & 7;
  int wg = (xcd < r8 ? xcd * (q8 + 1) : r8 * (q8 + 1) + (xcd - r8) * q8) + idx;
  int tileM = (wg / ntn) * 256, tileN = (wg % ntn) * 256;

  int wr = wave >> 2, wc = wave & 3;       // 2M x 4N; per-wave 128 x 64
  int wbM = wr * 128, wbN = wc * 64;

  f32x4 acc[8][4] = {};

  const char* Ag = (const char*)A + (size_t)tileM * 1024;
  const char* Bg = (const char*)Bt + (size_t)tileN * 1024;

  // row/chunk addressing constants for ds_read
  int arow[8], brow[4];
#pragma unroll
  for (int fm = 0; fm < 8; ++fm) arow[fm] = wbM + fm * 16 + r16;
#pragma unroll
  for (int fn = 0; fn < 4; ++fn) brow[fn] = wbN + fn * 16 + r16;

  // prologue: stage K-tiles 0,1 into slots 0,1 (8 loads outstanding)
  stage_panel(Ag, 0, smem, wave, lane);
  stage_panel(Bg, 0, smem + BOFF, wave, lane);
  stage_panel(Ag, 64, smem + SLOT, wave, lane);
  stage_panel(Bg, 64, smem + SLOT + BOFF, wave, lane);

#pragma unroll
  for (int kt = 0; kt < 16; ++kt) {
    // ---- boundary: tile kt fully visible to ALL waves (waitv then barrier)
    if (kt < 15) waitv<4>(); else waitv<0>();
    PHASE_SEP();
    __builtin_amdgcn_s_barrier();
    PHASE_SEP();

    const char* cb = smem + (kt & 3) * SLOT;
    char* nb = smem + ((kt + 2) & 3) * SLOT;
    bool st = kt < 14;

    // ======== phase 1: read B fn0-3 + A fm0-3 ; stage A(kt+2) ; 16 MFMA ====
    bf16x8 bfr[4], afr[4];
#pragma unroll
    for (int fn = 0; fn < 4; ++fn)
      bfr[fn] = *(const bf16x8*)(cb + BOFF + brow[fn] * 64 +
                                 ((r4 ^ ((brow[fn] >> 1) & 3)) << 4));
#pragma unroll
    for (int fm = 0; fm < 4; ++fm)
      afr[fm] = *(const bf16x8*)(cb + arow[fm] * 64 +
                                 ((r4 ^ ((arow[fm] >> 1) & 3)) << 4));
    if (st) stage_panel(Ag, (kt + 2) * 64, nb, wave, lane);
    PHASE_SEP();
    __builtin_amdgcn_s_barrier();
    asm volatile("s_waitcnt lgkmcnt(0)" ::: "memory");
    PHASE_SEP();
    __builtin_amdgcn_s_setprio(1);
#pragma unroll
    for (int fm = 0; fm < 4; ++fm)
#pragma unroll
      for (int fn = 0; fn < 4; ++fn)
        acc[fm][fn] = __builtin_amdgcn_mfma_f32_16x16x32_bf16(afr[fm], bfr[fn],
                                                              acc[fm][fn], 0, 0, 0);
    __builtin_amdgcn_s_setprio(0);
    PHASE_SEP();
    __builtin_amdgcn_s_barrier();
    PHASE_SEP();

    // ======== phase 2: read A fm4-7 ; stage B(kt+2) ; 16 MFMA ==============
    bf16x8 afr2[4];
#pragma unroll
    for (int fm = 0; fm < 4; ++fm)
      afr2[fm] = *(const bf16x8*)(cb + arow[fm + 4] * 64 +
                                  ((r4 ^ ((arow[fm + 4] >> 1) & 3)) << 4));
    if (st) stage_panel(Bg, (kt + 2) * 64, nb + BOFF, wave, lane);
    PHASE_SEP();
    __builtin_amdgcn_s_barrier();
    asm volatile("s_waitcnt lgkmcnt(0)" ::: "memory");
    PHASE_SEP();
    __builtin_amdgcn_s_setprio(1);
#pragma unroll
    for (int fm = 0; fm < 4; ++fm)
#pragma unroll
      for (int fn = 0; fn < 4; ++fn)
        acc[fm + 4][fn] = __builtin_amdgcn_mfma_f32_16x16x32_bf16(afr2[fm], bfr[fn],
                                                                  acc[fm + 4][fn], 0, 0, 0);
    __builtin_amdgcn_s_setprio(0);
    PHASE_SEP();
    __builtin_amdgcn_s_barrier();
    PHASE_SEP();
  }

  // epilogue: C/D layout col=lane&15, row=(lane>>4)*4+reg [m89-verified]
#pragma unroll
  for (int fm = 0; fm < 8; ++fm) {
    int gmb = tileM + wbM + fm * 16 + r4 * 4;
#pragma unroll
    for (int fn = 0; fn < 4; ++fn) {
      int gn = tileN + wbN + fn * 16 + r16;
      float bv = bias[gn];
      if constexpr (EPI == 0) {
        int sel = gn >> 9;          // 0=q, 1=k, 2=v
        int n2 = gn & 511;
        int hh = n2 >> 6, dd = n2 & 63;
#pragma unroll
        for (int rr = 0; rr < 4; ++rr) {
          int gm = gmb + rr;
          int bb = gm / 87, tt = gm - bb * 87;
          __hip_bfloat16 hv = __float2bfloat16(acc[fm][fn][rr] + bv);
          if (sel == 0)
            ((__hip_bfloat16*)o0)[((size_t)(bb * 8 + hh) * 96 + tt) * 64 + dd] = hv;
          else if (sel == 1)
            ((__hip_bfloat16*)o1)[((size_t)(bb * 8 + hh) * 96 + tt) * 64 + dd] = hv;
          else
            ((__hip_bfloat16*)o2)[((size_t)(bb * 8 + hh) * 64 + dd) * 96 + tt] = hv;
        }
      } else {
#pragma unroll
        for (int rr = 0; rr < 4; ++rr)
          ((float*)o0)[(size_t)(gmb + rr) * 512 + gn] = acc[fm][fn][rr] + bv;
      }
    }
  }
}

// ---------------- attention per (b,h) (unchanged) ----------------
__global__ __launch_bounds__(256) void attn_kernel(
    const __hip_bfloat16* __restrict__ q_ws, const __hip_bfloat16* __restrict__ k_ws,
    const __hip_bfloat16* __restrict__ vt_ws, __hip_bfloat16* __restrict__ y_ws) {
  __shared__ __align__(16) char smem[73728];
  __hip_bfloat16* Qs  = (__hip_bfloat16*)smem;             // [96][64] 12KB
  __hip_bfloat16* Ks  = (__hip_bfloat16*)(smem + 12288);   // [96][64] 12KB
  __hip_bfloat16* Vts = (__hip_bfloat16*)(smem + 24576);   // [64][96] 12KB
  float* Sb           = (float*)(smem + 36864);            // [96][96] fp32 36KB
  __hip_bfloat16* Pb  = (__hip_bfloat16*)smem;             // [96][96] aliases Qs+Ks

  int tid = threadIdx.x, lane = tid & 63, wave = tid >> 6;
  int bh = blockIdx.x, b = bh >> 3, h = bh & 7;
  int r16 = lane & 15, r4 = lane >> 4;

  {
    const bf16x8* gq = (const bf16x8*)(q_ws + (size_t)bh * 6144);
    const bf16x8* gk = (const bf16x8*)(k_ws + (size_t)bh * 6144);
    const bf16x8* gv = (const bf16x8*)(vt_ws + (size_t)bh * 6144);
    bf16x8* lq = (bf16x8*)Qs; bf16x8* lk = (bf16x8*)Ks; bf16x8* lv = (bf16x8*)Vts;
    for (int i = tid; i < 768; i += 256) { lq[i] = gq[i]; lk[i] = gk[i]; lv[i] = gv[i]; }
  }
  __syncthreads();

  // S = Q K^T : 6x6 16-tiles, K=64
  for (int p = 0; p < 9; ++p) {
    int pair = wave + p * 4;
    int mt = pair / 6, nt = pair - mt * 6;
    f32x4 acc = {0.f, 0.f, 0.f, 0.f};
#pragma unroll
    for (int kk = 0; kk < 2; ++kk) {
      bf16x8 a  = *(const bf16x8*)(Qs + (mt * 16 + r16) * 64 + kk * 32 + r4 * 8);
      bf16x8 bb = *(const bf16x8*)(Ks + (nt * 16 + r16) * 64 + kk * 32 + r4 * 8);
      acc = __builtin_amdgcn_mfma_f32_16x16x32_bf16(a, bb, acc, 0, 0, 0);
    }
    int row0 = mt * 16 + r4 * 4, col = nt * 16 + r16;
#pragma unroll
    for (int r = 0; r < 4; ++r) Sb[(row0 + r) * 96 + col] = acc[r];
  }
  __syncthreads();

  // masked softmax, one 32-lane group per row
  int group = tid >> 5, glane = tid & 31;
  for (int r = group; r < 96; r += 8) {
    if (r < 87) {
      int lr = mod29(r);
      float sv[3]; bool al[3];
      float mx = -__builtin_inff();
#pragma unroll
      for (int q = 0; q < 3; ++q) {
        int j = glane + q * 32;
        int lj = mod29(j);
        al[q] = (j < 87) && (lj <= lr) && (lj >= lr - 21);
        sv[q] = al[q] ? Sb[r * 96 + j] * 0.125f : -__builtin_inff();
        mx = fmaxf(mx, sv[q]);
      }
#pragma unroll
      for (int o = 16; o >= 1; o >>= 1) mx = fmaxf(mx, __shfl_xor(mx, o, 32));
      float e[3], sum = 0.f;
#pragma unroll
      for (int q = 0; q < 3; ++q) { e[q] = al[q] ? __expf(sv[q] - mx) : 0.f; sum += e[q]; }
#pragma unroll
      for (int o = 16; o >= 1; o >>= 1) sum += __shfl_xor(sum, o, 32);
      float inv = 1.f / sum;
#pragma unroll
      for (int q = 0; q < 3; ++q)
        Pb[r * 96 + glane + q * 32] = __float2bfloat16(e[q] * inv);
    } else {
#pragma unroll
      for (int q = 0; q < 3; ++q) Pb[r * 96 + glane + q * 32] = __float2bfloat16(0.f);
    }
  }
  __syncthreads();

  // Y = P V : A=P [96][96], Bt=Vt [64][96], 6x4 16-tiles, K=96
  for (int p = 0; p < 6; ++p) {
    int pair = wave + p * 4;
    int mt = pair >> 2, nt = pair & 3;
    f32x4 acc = {0.f, 0.f, 0.f, 0.f};
#pragma unroll
    for (int kk = 0; kk < 3; ++kk) {
      bf16x8 a  = *(const bf16x8*)(Pb + (mt * 16 + r16) * 96 + kk * 32 + r4 * 8);
      bf16x8 bb = *(const bf16x8*)(Vts + (nt * 16 + r16) * 96 + kk * 32 + r4 * 8);
      acc = __builtin_amdgcn_mfma_f32_16x16x32_bf16(a, bb, acc, 0, 0, 0);
    }
    int t0 = mt * 16 + r4 * 4, d = nt * 16 + r16;
#pragma unroll
    for (int r = 0; r < 4; ++r) {
      int t = t0 + r;
      if (t < 87)
        y_ws[((size_t)b * 87 + t) * 512 + h * 64 + d] = __float2bfloat16(acc[r]);
    }
  }
}

// ---------------- launch ----------------
extern "C" void kernel_launch(void* const* d_in, const int* in_sizes, int n_in,
                              void* d_out, int out_size, void* d_ws, size_t ws_size,
                              hipStream_t stream) {
  const float* x  = (const float*)d_in[0];
  const float* Wq = (const float*)d_in[1];
  const float* bq = (const float*)d_in[2];
  const float* Wk = (const float*)d_in[3];
  const float* bk = (const float*)d_in[4];
  const float* Wv = (const float*)d_in[5];
  const float* bv = (const float*)d_in[6];
  const float* Wp = (const float*)d_in[7];
  const float* bp = (const float*)d_in[8];
  float* out = (float*)d_out;

  char* ws = (char*)d_ws;
  size_t off = 0;
  __hip_bfloat16* xb    = (__hip_bfloat16*)(ws + off); off += (size_t)BT_ * 512 * 2;
  __hip_bfloat16* wqkv  = (__hip_bfloat16*)(ws + off); off += 1536 * 512 * 2;
  __hip_bfloat16* wp    = (__hip_bfloat16*)(ws + off); off += 512 * 512 * 2;
  float*          biasc = (float*)(ws + off);          off += 8192;
  __hip_bfloat16* q_ws  = (__hip_bfloat16*)(ws + off); off += (size_t)BH_ * 6144 * 2;
  __hip_bfloat16* k_ws  = (__hip_bfloat16*)(ws + off); off += (size_t)BH_ * 6144 * 2;
  __hip_bfloat16* vt_ws = (__hip_bfloat16*)(ws + off); off += (size_t)BH_ * 6144 * 2;
  __hip_bfloat16* yb = xb;  // alias: xb fully consumed by gemm_qkv before attn writes y

  if (ws_size < off) return;

  convert_x_kernel<<<2048, 256, 0, stream>>>(x, xb, BT_ * 512 / 4);
  convert_w_kernel<<<1024, 256, 0, stream>>>(Wq, Wk, Wv, Wp, bq, bk, bv, wqkv, wp, biasc);
  zero_pads_kernel<<<2048, 256, 0, stream>>>(q_ws, k_ws, vt_ws);
  // qkv: 256x256 tiles -> 174 x 6 = 1044 blocks
  gemm8_kernel<0><<<1044, 512, 0, stream>>>(xb, wqkv, biasc, 6, q_ws, k_ws, vt_ws);
  attn_kernel<<<BH_, 256, 0, stream>>>(q_ws, k_ws, vt_ws, yb);
  // proj: 256x256 tiles -> 174 x 2 = 348 blocks
  gemm8_kernel<1><<<348, 512, 0, stream>>>(yb, wp, bp, 2, out, nullptr, nullptr);
}

// Round 10
// 268.836 us; speedup vs baseline: 1.2610x; 1.2610x over previous
//
#include <hip/hip_runtime.h>
#include <hip/hip_bf16.h>
#include <stdint.h>

// Problem constants
#define B_   512
#define T_   87
#define C_   512
#define H_   8
#define D_   64
#define BT_  44544        // B_*T_
#define BH_  4096         // B_*H_

typedef __attribute__((ext_vector_type(4))) float f32x4;
typedef __attribute__((ext_vector_type(8))) __bf16 bf16x8;
typedef __attribute__((ext_vector_type(4))) unsigned short u16x4;

__device__ __forceinline__ int mod29(int x) {
  return x < 29 ? x : (x < 58 ? x - 29 : x - 58);
}

// ---------------- converts ----------------

__global__ void convert_x_kernel(const float* __restrict__ x,
                                 __hip_bfloat16* __restrict__ xb, int n4) {
  int stride = gridDim.x * blockDim.x;
  for (int i = blockIdx.x * blockDim.x + threadIdx.x; i < n4; i += stride) {
    f32x4 v = ((const f32x4*)x)[i];
    u16x4 o;
    o.x = __builtin_bit_cast(unsigned short, __float2bfloat16(v.x));
    o.y = __builtin_bit_cast(unsigned short, __float2bfloat16(v.y));
    o.z = __builtin_bit_cast(unsigned short, __float2bfloat16(v.z));
    o.w = __builtin_bit_cast(unsigned short, __float2bfloat16(v.w));
    ((u16x4*)xb)[i] = o;
  }
}

__global__ void convert_w_kernel(const float* __restrict__ Wq, const float* __restrict__ Wk,
                                 const float* __restrict__ Wv, const float* __restrict__ Wp,
                                 const float* __restrict__ bq, const float* __restrict__ bk,
                                 const float* __restrict__ bv,
                                 __hip_bfloat16* __restrict__ wqkv,
                                 __hip_bfloat16* __restrict__ wp,
                                 float* __restrict__ biasc) {
  const int NW = 262144;                 // 512*512
  const int total = 3 * NW + NW + 1536;
  int stride = gridDim.x * blockDim.x;
  for (int i = blockIdx.x * blockDim.x + threadIdx.x; i < total; i += stride) {
    if (i < 3 * NW) {
      float v = (i < NW) ? Wq[i] : (i < 2 * NW ? Wk[i - NW] : Wv[i - 2 * NW]);
      wqkv[i] = __float2bfloat16(v);
    } else if (i < 4 * NW) {
      wp[i - 3 * NW] = __float2bfloat16(Wp[i - 3 * NW]);
    } else {
      int j = i - 4 * NW;
      biasc[j] = (j < 512) ? bq[j] : (j < 1024 ? bk[j - 512] : bv[j - 1024]);
    }
  }
}

// ---------------- reg-staged GEMM (R7 core, unchanged), new bounce epilogue ---
// LDS: 2 buffers x (A 16KB + B 16KB) = 64KB -> 2 blocks/CU.
// Swizzle on ds_write: 16B slot s of row r holds global chunk s^(r&7).

template<int FM, int FN>
__device__ __forceinline__ void compute_tile(const char* Ab, const char* Bb,
                                             int wbM, int wbN, int r16, int r4,
                                             f32x4 acc[FM][FN]) {
  const int cxor = (r16 & 7) << 4;
  bf16x8 bf[FN][2];
#pragma unroll
  for (int fn = 0; fn < FN; ++fn) {
    int row = wbN + fn * 16 + r16;
#pragma unroll
    for (int kk = 0; kk < 2; ++kk)
      bf[fn][kk] = *(const bf16x8*)(Bb + row * 128 + ((kk * 64 + r4 * 16) ^ cxor));
  }
#pragma unroll
  for (int fm = 0; fm < FM; ++fm) {
    int row = wbM + fm * 16 + r16;
    bf16x8 a0 = *(const bf16x8*)(Ab + row * 128 + ((r4 * 16) ^ cxor));
    bf16x8 a1 = *(const bf16x8*)(Ab + row * 128 + ((64 + r4 * 16) ^ cxor));
#pragma unroll
    for (int fn = 0; fn < FN; ++fn) {
      acc[fm][fn] = __builtin_amdgcn_mfma_f32_16x16x32_bf16(a0, bf[fn][0], acc[fm][fn], 0, 0, 0);
      acc[fm][fn] = __builtin_amdgcn_mfma_f32_16x16x32_bf16(a1, bf[fn][1], acc[fm][fn], 0, 0, 0);
    }
  }
}

// EPI 0: qkv row-major outputs (o0=q,o1=k,o2=v, bias=biasc). EPI 1: proj fp32.
template<int EPI>
__global__ __launch_bounds__(256) void gemmr_kernel(
    const __hip_bfloat16* __restrict__ A, const __hip_bfloat16* __restrict__ Bt,
    const float* __restrict__ bias, int ntn,
    void* __restrict__ o0, void* __restrict__ o1, void* __restrict__ o2) {
  __shared__ __align__(16) char smem[2][2][16384];  // [buf][A|B][128 rows x 128B]

  int tid = threadIdx.x, lane = tid & 63, wave = tid >> 6;
  int r16 = lane & 15, r4 = lane >> 4;

  int nwg = gridDim.x;
  int wg = (blockIdx.x & 7) * (nwg >> 3) + (blockIdx.x >> 3);
  int tileM = (wg / ntn) * 128, tileN = (wg % ntn) * 128;

  int wr = wave >> 1, wc = wave & 1;       // per-wave 64x64
  int wbM = wr * 64, wbN = wc * 64;

  const int rbase = tid >> 3, c = tid & 7;
  const int cs = (c ^ (rbase & 7)) << 4;
  const char* Ag = (const char*)A + (size_t)(tileM + rbase) * 1024 + c * 16;
  const char* Bg = (const char*)Bt + (size_t)(tileN + rbase) * 1024 + c * 16;

  f32x4 acc[4][4] = {};
  bf16x8 rA[4], rB[4];

#pragma unroll
  for (int j = 0; j < 4; ++j) {
    rA[j] = *(const bf16x8*)(Ag + (size_t)j * 32768);
    rB[j] = *(const bf16x8*)(Bg + (size_t)j * 32768);
  }
#pragma unroll
  for (int j = 0; j < 4; ++j) {
    *(bf16x8*)(&smem[0][0][0] + (rbase + 32 * j) * 128 + cs) = rA[j];
    *(bf16x8*)(&smem[0][1][0] + (rbase + 32 * j) * 128 + cs) = rB[j];
  }
  __syncthreads();

#pragma unroll
  for (int kt = 0; kt < 8; ++kt) {
    int cur = kt & 1;
    if (kt < 7) {
#pragma unroll
      for (int j = 0; j < 4; ++j) {
        rA[j] = *(const bf16x8*)(Ag + (size_t)j * 32768 + (kt + 1) * 128);
        rB[j] = *(const bf16x8*)(Bg + (size_t)j * 32768 + (kt + 1) * 128);
      }
    }
    __builtin_amdgcn_s_setprio(1);
    compute_tile<4, 4>(&smem[cur][0][0], &smem[cur][1][0], wbM, wbN, r16, r4, acc);
    __builtin_amdgcn_s_setprio(0);
    if (kt < 7) {
#pragma unroll
      for (int j = 0; j < 4; ++j) {
        *(bf16x8*)(&smem[cur ^ 1][0][0] + (rbase + 32 * j) * 128 + cs) = rA[j];
        *(bf16x8*)(&smem[cur ^ 1][1][0] + (rbase + 32 * j) * 128 + cs) = rB[j];
      }
    }
    __syncthreads();
  }

  // ---- bounce epilogue: frag -> per-wave LDS scratch -> coalesced stores ----
  if constexpr (EPI == 0) {
    char* scratch = &smem[0][0][0] + wave * 2304;      // 16 rows x 144B
    int gn0 = tileN + wbN;                             // head-aligned (64 | gn0)
    int sel = gn0 >> 9;                                // 0=q 1=k 2=v
    int hh = (gn0 & 511) >> 6;
    __hip_bfloat16* obase = (sel == 0) ? (__hip_bfloat16*)o0
                          : (sel == 1) ? (__hip_bfloat16*)o1 : (__hip_bfloat16*)o2;
#pragma unroll
    for (int fm = 0; fm < 4; ++fm) {
#pragma unroll
      for (int fn = 0; fn < 4; ++fn) {
        float bv = bias[gn0 + fn * 16 + r16];
#pragma unroll
        for (int rr = 0; rr < 4; ++rr)
          *(__hip_bfloat16*)(scratch + (r4 * 4 + rr) * 144 + (fn * 16 + r16) * 2) =
              __float2bfloat16(acc[fm][fn][rr] + bv);
      }
#pragma unroll
      for (int p = 0; p < 2; ++p) {
        bf16x8 vrow = *(const bf16x8*)(scratch + (p * 8 + (lane >> 3)) * 144 + (lane & 7) * 16);
        int gm = tileM + wbM + fm * 16 + p * 8 + (lane >> 3);
        int bb = gm / 87, tt = gm - bb * 87;
        *(bf16x8*)(obase + ((size_t)(bb * 8 + hh) * 96 + tt) * 64 + (lane & 7) * 8) = vrow;
      }
    }
  } else {
    char* scratch = &smem[0][0][0] + wave * 4352;      // 16 rows x 272B
#pragma unroll
    for (int fm = 0; fm < 4; ++fm) {
#pragma unroll
      for (int fn = 0; fn < 4; ++fn) {
        float bv = bias[tileN + wbN + fn * 16 + r16];
#pragma unroll
        for (int rr = 0; rr < 4; ++rr)
          *(float*)(scratch + (r4 * 4 + rr) * 272 + (fn * 16 + r16) * 4) =
              acc[fm][fn][rr] + bv;
      }
#pragma unroll
      for (int p = 0; p < 4; ++p) {
        f32x4 vr = *(const f32x4*)(scratch + (p * 4 + (lane >> 4)) * 272 + (lane & 15) * 16);
        int gm = tileM + wbM + fm * 16 + p * 4 + (lane >> 4);
        *(f32x4*)((float*)o0 + (size_t)gm * 512 + tileN + wbN + (lane & 15) * 4) = vr;
      }
    }
  }
}

// ---------------- attention per (b,h): padded LDS, V transposed on stage ------
// LDS (bytes): Qs[96 x 144B] @0 ; Ks @13824 ; Vt[64 x 208B] @27648 ;
// Sb[96][96] f32 @40960 ; Pb[96 x 208B] aliases @0. Total 77824 -> 2 blocks/CU.
#define QS_O  0
#define KS_O  13824
#define VT_O  27648
#define SB_O  40960
#define PB_O  0

__global__ __launch_bounds__(256) void attn_kernel(
    const __hip_bfloat16* __restrict__ q_ws, const __hip_bfloat16* __restrict__ k_ws,
    const __hip_bfloat16* __restrict__ v_ws, __hip_bfloat16* __restrict__ y_ws) {
  __shared__ __align__(16) char smem[77824];
  float* Sb = (float*)(smem + SB_O);

  int tid = threadIdx.x, lane = tid & 63, wave = tid >> 6;
  int bh = blockIdx.x, b = bh >> 3, h = bh & 7;
  int r16 = lane & 15, r4 = lane >> 4;

  {
    const bf16x8* gq = (const bf16x8*)(q_ws + (size_t)bh * 6144);
    const bf16x8* gk = (const bf16x8*)(k_ws + (size_t)bh * 6144);
    const bf16x8* gv = (const bf16x8*)(v_ws + (size_t)bh * 6144);
    for (int i = tid; i < 768; i += 256) {
      int row = i >> 3, ch = i & 7;
      *(bf16x8*)(smem + QS_O + row * 144 + ch * 16) = gq[i];
      *(bf16x8*)(smem + KS_O + row * 144 + ch * 16) = gk[i];
      bf16x8 v8 = gv[i];                 // v row-major: row t=row, cols d0..d0+7
      int d0 = ch * 8;
#pragma unroll
      for (int e = 0; e < 8; ++e)
        *(__bf16*)(smem + VT_O + (d0 + e) * 208 + row * 2) = v8[e];
    }
  }
  __syncthreads();

  // S = Q K^T : 6x6 16-tiles, K=64
  for (int p = 0; p < 9; ++p) {
    int pair = wave + p * 4;
    int mt = pair / 6, nt = pair - mt * 6;
    f32x4 acc = {0.f, 0.f, 0.f, 0.f};
#pragma unroll
    for (int kk = 0; kk < 2; ++kk) {
      bf16x8 a  = *(const bf16x8*)(smem + QS_O + (mt * 16 + r16) * 144 + kk * 64 + r4 * 16);
      bf16x8 bb = *(const bf16x8*)(smem + KS_O + (nt * 16 + r16) * 144 + kk * 64 + r4 * 16);
      acc = __builtin_amdgcn_mfma_f32_16x16x32_bf16(a, bb, acc, 0, 0, 0);
    }
    int row0 = mt * 16 + r4 * 4, col = nt * 16 + r16;
#pragma unroll
    for (int r = 0; r < 4; ++r) Sb[(row0 + r) * 96 + col] = acc[r];
  }
  __syncthreads();

  // masked softmax, one 32-lane group per row; P written @PB_O (208B pitch)
  int group = tid >> 5, glane = tid & 31;
  for (int r = group; r < 96; r += 8) {
    if (r < 87) {
      int lr = mod29(r);
      float sv[3]; bool al[3];
      float mx = -__builtin_inff();
#pragma unroll
      for (int q = 0; q < 3; ++q) {
        int j = glane + q * 32;
        int lj = mod29(j);
        al[q] = (j < 87) && (lj <= lr) && (lj >= lr - 21);
        sv[q] = al[q] ? Sb[r * 96 + j] * 0.125f : -__builtin_inff();
        mx = fmaxf(mx, sv[q]);
      }
#pragma unroll
      for (int o = 16; o >= 1; o >>= 1) mx = fmaxf(mx, __shfl_xor(mx, o, 32));
      float e[3], sum = 0.f;
#pragma unroll
      for (int q = 0; q < 3; ++q) { e[q] = al[q] ? __expf(sv[q] - mx) : 0.f; sum += e[q]; }
#pragma unroll
      for (int o = 16; o >= 1; o >>= 1) sum += __shfl_xor(sum, o, 32);
      float inv = 1.f / sum;
#pragma unroll
      for (int q = 0; q < 3; ++q)
        *(__hip_bfloat16*)(smem + PB_O + r * 208 + (glane + q * 32) * 2) =
            __float2bfloat16(e[q] * inv);
    } else {
#pragma unroll
      for (int q = 0; q < 3; ++q)
        *(__hip_bfloat16*)(smem + PB_O + r * 208 + (glane + q * 32) * 2) =
            __float2bfloat16(0.f);
    }
  }
  __syncthreads();

  // Y = P V : A=P rows t (208B pitch), B=Vt rows d (208B pitch), K=96
  for (int p = 0; p < 6; ++p) {
    int pair = wave + p * 4;
    int mt = pair >> 2, nt = pair & 3;
    f32x4 acc = {0.f, 0.f, 0.f, 0.f};
#pragma unroll
    for (int kk = 0; kk < 3; ++kk) {
      bf16x8 a  = *(const bf16x8*)(smem + PB_O + (mt * 16 + r16) * 208 + kk * 64 + r4 * 16);
      bf16x8 bb = *(const bf16x8*)(smem + VT_O + (nt * 16 + r16) * 208 + kk * 64 + r4 * 16);
      acc = __builtin_amdgcn_mfma_f32_16x16x32_bf16(a, bb, acc, 0, 0, 0);
    }
    int t0 = mt * 16 + r4 * 4, d = nt * 16 + r16;
#pragma unroll
    for (int r = 0; r < 4; ++r) {
      int t = t0 + r;
      if (t < 87)
        y_ws[((size_t)b * 87 + t) * 512 + h * 64 + d] = __float2bfloat16(acc[r]);
    }
  }
}

// ---------------- launch ----------------
extern "C" void kernel_launch(void* const* d_in, const int* in_sizes, int n_in,
                              void* d_out, int out_size, void* d_ws, size_t ws_size,
                              hipStream_t stream) {
  const float* x  = (const float*)d_in[0];
  const float* Wq = (const float*)d_in[1];
  const float* bq = (const float*)d_in[2];
  const float* Wk = (const float*)d_in[3];
  const float* bk = (const float*)d_in[4];
  const float* Wv = (const float*)d_in[5];
  const float* bv = (const float*)d_in[6];
  const float* Wp = (const float*)d_in[7];
  const float* bp = (const float*)d_in[8];
  float* out = (float*)d_out;

  char* ws = (char*)d_ws;
  size_t off = 0;
  __hip_bfloat16* xb    = (__hip_bfloat16*)(ws + off); off += (size_t)BT_ * 512 * 2;
  __hip_bfloat16* wqkv  = (__hip_bfloat16*)(ws + off); off += 1536 * 512 * 2;
  __hip_bfloat16* wp    = (__hip_bfloat16*)(ws + off); off += 512 * 512 * 2;
  float*          biasc = (float*)(ws + off);          off += 8192;
  __hip_bfloat16* q_ws  = (__hip_bfloat16*)(ws + off); off += (size_t)BH_ * 6144 * 2;
  __hip_bfloat16* k_ws  = (__hip_bfloat16*)(ws + off); off += (size_t)BH_ * 6144 * 2;
  __hip_bfloat16* v_ws  = (__hip_bfloat16*)(ws + off); off += (size_t)BH_ * 6144 * 2;
  __hip_bfloat16* yb = xb;  // alias: xb fully consumed by gemm_qkv before attn writes y

  if (ws_size < off) return;

  convert_x_kernel<<<2048, 256, 0, stream>>>(x, xb, BT_ * 512 / 4);
  convert_w_kernel<<<1024, 256, 0, stream>>>(Wq, Wk, Wv, Wp, bq, bk, bv, wqkv, wp, biasc);
  // qkv: 128x128 tiles -> 348 x 12 = 4176 blocks (div by 8)
  gemmr_kernel<0><<<4176, 256, 0, stream>>>(xb, wqkv, biasc, 12, q_ws, k_ws, v_ws);
  attn_kernel<<<BH_, 256, 0, stream>>>(q_ws, k_ws, v_ws, yb);
  // proj: 128x128 tiles -> 348 x 4 = 1392 blocks (div by 8)
  gemmr_kernel<1><<<1392, 256, 0, stream>>>(yb, wp, bp, 4, out, nullptr, nullptr);
}

// Round 11
// 237.743 us; speedup vs baseline: 1.4259x; 1.1308x over previous
//
#include <hip/hip_runtime.h>
#include <hip/hip_bf16.h>
#include <stdint.h>

// Problem constants
#define B_   512
#define T_   87
#define C_   512
#define H_   8
#define D_   64
#define BT_  44544        // B_*T_
#define BH_  4096         // B_*H_

typedef __attribute__((ext_vector_type(4))) float f32x4;
typedef __attribute__((ext_vector_type(8))) __bf16 bf16x8;
typedef __attribute__((ext_vector_type(4))) unsigned short u16x4;

__device__ __forceinline__ int mod29(int x) {
  return x < 29 ? x : (x < 58 ? x - 29 : x - 58);
}

// ---------------- converts ----------------

__global__ void convert_x_kernel(const float* __restrict__ x,
                                 __hip_bfloat16* __restrict__ xb, int n4) {
  int stride = gridDim.x * blockDim.x;
  for (int i = blockIdx.x * blockDim.x + threadIdx.x; i < n4; i += stride) {
    f32x4 v = ((const f32x4*)x)[i];
    u16x4 o;
    o.x = __builtin_bit_cast(unsigned short, __float2bfloat16(v.x));
    o.y = __builtin_bit_cast(unsigned short, __float2bfloat16(v.y));
    o.z = __builtin_bit_cast(unsigned short, __float2bfloat16(v.z));
    o.w = __builtin_bit_cast(unsigned short, __float2bfloat16(v.w));
    ((u16x4*)xb)[i] = o;
  }
}

__global__ void convert_w_kernel(const float* __restrict__ Wq, const float* __restrict__ Wk,
                                 const float* __restrict__ Wv, const float* __restrict__ Wp,
                                 const float* __restrict__ bq, const float* __restrict__ bk,
                                 const float* __restrict__ bv,
                                 __hip_bfloat16* __restrict__ wqkv,
                                 __hip_bfloat16* __restrict__ wp,
                                 float* __restrict__ biasc) {
  const int NW = 262144;                 // 512*512
  const int total = 3 * NW + NW + 1536;
  int stride = gridDim.x * blockDim.x;
  for (int i = blockIdx.x * blockDim.x + threadIdx.x; i < total; i += stride) {
    if (i < 3 * NW) {
      float v = (i < NW) ? Wq[i] : (i < 2 * NW ? Wk[i - NW] : Wv[i - 2 * NW]);
      wqkv[i] = __float2bfloat16(v);
    } else if (i < 4 * NW) {
      wp[i - 3 * NW] = __float2bfloat16(Wp[i - 3 * NW]);
    } else {
      int j = i - 4 * NW;
      biasc[j] = (j < 512) ? bq[j] : (j < 1024 ? bk[j - 512] : bv[j - 1024]);
    }
  }
}

// ---------------- reg-staged GEMM (R7 core), bounce epilogue (R10) -----------

template<int FM, int FN>
__device__ __forceinline__ void compute_tile(const char* Ab, const char* Bb,
                                             int wbM, int wbN, int r16, int r4,
                                             f32x4 acc[FM][FN]) {
  const int cxor = (r16 & 7) << 4;
  bf16x8 bf[FN][2];
#pragma unroll
  for (int fn = 0; fn < FN; ++fn) {
    int row = wbN + fn * 16 + r16;
#pragma unroll
    for (int kk = 0; kk < 2; ++kk)
      bf[fn][kk] = *(const bf16x8*)(Bb + row * 128 + ((kk * 64 + r4 * 16) ^ cxor));
  }
#pragma unroll
  for (int fm = 0; fm < FM; ++fm) {
    int row = wbM + fm * 16 + r16;
    bf16x8 a0 = *(const bf16x8*)(Ab + row * 128 + ((r4 * 16) ^ cxor));
    bf16x8 a1 = *(const bf16x8*)(Ab + row * 128 + ((64 + r4 * 16) ^ cxor));
#pragma unroll
    for (int fn = 0; fn < FN; ++fn) {
      acc[fm][fn] = __builtin_amdgcn_mfma_f32_16x16x32_bf16(a0, bf[fn][0], acc[fm][fn], 0, 0, 0);
      acc[fm][fn] = __builtin_amdgcn_mfma_f32_16x16x32_bf16(a1, bf[fn][1], acc[fm][fn], 0, 0, 0);
    }
  }
}

// EPI 0: qkv row-major outputs (o0=q,o1=k,o2=v, bias=biasc). EPI 1: proj fp32.
template<int EPI>
__global__ __launch_bounds__(256) void gemmr_kernel(
    const __hip_bfloat16* __restrict__ A, const __hip_bfloat16* __restrict__ Bt,
    const float* __restrict__ bias, int ntn,
    void* __restrict__ o0, void* __restrict__ o1, void* __restrict__ o2) {
  __shared__ __align__(16) char smem[2][2][16384];  // [buf][A|B][128 rows x 128B]

  int tid = threadIdx.x, lane = tid & 63, wave = tid >> 6;
  int r16 = lane & 15, r4 = lane >> 4;

  int nwg = gridDim.x;
  int wg = (blockIdx.x & 7) * (nwg >> 3) + (blockIdx.x >> 3);
  int tileM = (wg / ntn) * 128, tileN = (wg % ntn) * 128;

  int wr = wave >> 1, wc = wave & 1;       // per-wave 64x64
  int wbM = wr * 64, wbN = wc * 64;

  const int rbase = tid >> 3, c = tid & 7;
  const int cs = (c ^ (rbase & 7)) << 4;
  const char* Ag = (const char*)A + (size_t)(tileM + rbase) * 1024 + c * 16;
  const char* Bg = (const char*)Bt + (size_t)(tileN + rbase) * 1024 + c * 16;

  f32x4 acc[4][4] = {};
  bf16x8 rA[4], rB[4];

#pragma unroll
  for (int j = 0; j < 4; ++j) {
    rA[j] = *(const bf16x8*)(Ag + (size_t)j * 32768);
    rB[j] = *(const bf16x8*)(Bg + (size_t)j * 32768);
  }
#pragma unroll
  for (int j = 0; j < 4; ++j) {
    *(bf16x8*)(&smem[0][0][0] + (rbase + 32 * j) * 128 + cs) = rA[j];
    *(bf16x8*)(&smem[0][1][0] + (rbase + 32 * j) * 128 + cs) = rB[j];
  }
  __syncthreads();

#pragma unroll
  for (int kt = 0; kt < 8; ++kt) {
    int cur = kt & 1;
    if (kt < 7) {
#pragma unroll
      for (int j = 0; j < 4; ++j) {
        rA[j] = *(const bf16x8*)(Ag + (size_t)j * 32768 + (kt + 1) * 128);
        rB[j] = *(const bf16x8*)(Bg + (size_t)j * 32768 + (kt + 1) * 128);
      }
    }
    __builtin_amdgcn_s_setprio(1);
    compute_tile<4, 4>(&smem[cur][0][0], &smem[cur][1][0], wbM, wbN, r16, r4, acc);
    __builtin_amdgcn_s_setprio(0);
    if (kt < 7) {
#pragma unroll
      for (int j = 0; j < 4; ++j) {
        *(bf16x8*)(&smem[cur ^ 1][0][0] + (rbase + 32 * j) * 128 + cs) = rA[j];
        *(bf16x8*)(&smem[cur ^ 1][1][0] + (rbase + 32 * j) * 128 + cs) = rB[j];
      }
    }
    __syncthreads();
  }

  // ---- bounce epilogue: frag -> per-wave LDS scratch -> coalesced stores ----
  if constexpr (EPI == 0) {
    char* scratch = &smem[0][0][0] + wave * 2304;      // 16 rows x 144B
    int gn0 = tileN + wbN;                             // head-aligned (64 | gn0)
    int sel = gn0 >> 9;                                // 0=q 1=k 2=v
    int hh = (gn0 & 511) >> 6;
    __hip_bfloat16* obase = (sel == 0) ? (__hip_bfloat16*)o0
                          : (sel == 1) ? (__hip_bfloat16*)o1 : (__hip_bfloat16*)o2;
#pragma unroll
    for (int fm = 0; fm < 4; ++fm) {
#pragma unroll
      for (int fn = 0; fn < 4; ++fn) {
        float bv = bias[gn0 + fn * 16 + r16];
#pragma unroll
        for (int rr = 0; rr < 4; ++rr)
          *(__hip_bfloat16*)(scratch + (r4 * 4 + rr) * 144 + (fn * 16 + r16) * 2) =
              __float2bfloat16(acc[fm][fn][rr] + bv);
      }
#pragma unroll
      for (int p = 0; p < 2; ++p) {
        bf16x8 vrow = *(const bf16x8*)(scratch + (p * 8 + (lane >> 3)) * 144 + (lane & 7) * 16);
        int gm = tileM + wbM + fm * 16 + p * 8 + (lane >> 3);
        int bb = gm / 87, tt = gm - bb * 87;
        *(bf16x8*)(obase + ((size_t)(bb * 8 + hh) * 96 + tt) * 64 + (lane & 7) * 8) = vrow;
      }
    }
  } else {
    char* scratch = &smem[0][0][0] + wave * 4352;      // 16 rows x 272B
#pragma unroll
    for (int fm = 0; fm < 4; ++fm) {
#pragma unroll
      for (int fn = 0; fn < 4; ++fn) {
        float bv = bias[tileN + wbN + fn * 16 + r16];
#pragma unroll
        for (int rr = 0; rr < 4; ++rr)
          *(float*)(scratch + (r4 * 4 + rr) * 272 + (fn * 16 + r16) * 4) =
              acc[fm][fn][rr] + bv;
      }
#pragma unroll
      for (int p = 0; p < 4; ++p) {
        f32x4 vr = *(const f32x4*)(scratch + (p * 4 + (lane >> 4)) * 272 + (lane & 15) * 16);
        int gm = tileM + wbM + fm * 16 + p * 4 + (lane >> 4);
        *(f32x4*)((float*)o0 + (size_t)gm * 512 + tileN + wbN + (lane & 15) * 4) = vr;
      }
    }
  }
}

// ---------------- attention per (b,h): in-register softmax, no Sb ------------
// LDS: Qs[96 x 144B] @0 ; Ks @13824 ; Vt[64 x 208B, chunk^=(d>>3)&3] @27648 ;
// Pb[96 x 208B] @40960. Total 60928 -> 2 blocks/CU.
#define QS_O  0
#define KS_O  13824
#define VT_O  27648
#define PB_O  40960

__global__ __launch_bounds__(256) void attn_kernel(
    const __hip_bfloat16* __restrict__ q_ws, const __hip_bfloat16* __restrict__ k_ws,
    const __hip_bfloat16* __restrict__ v_ws, __hip_bfloat16* __restrict__ y_ws) {
  __shared__ __align__(16) char smem[60928];

  int tid = threadIdx.x, lane = tid & 63, wave = tid >> 6;
  int bh = blockIdx.x, b = bh >> 3, h = bh & 7;
  int r16 = lane & 15, r4 = lane >> 4;

  {
    const bf16x8* gq = (const bf16x8*)(q_ws + (size_t)bh * 6144);
    const bf16x8* gk = (const bf16x8*)(k_ws + (size_t)bh * 6144);
    const bf16x8* gv = (const bf16x8*)(v_ws + (size_t)bh * 6144);
    for (int i = tid; i < 768; i += 256) {
      int row = i >> 3, ch = i & 7;
      *(bf16x8*)(smem + QS_O + row * 144 + ch * 16) = gq[i];
      *(bf16x8*)(smem + KS_O + row * 144 + ch * 16) = gk[i];
      bf16x8 v8 = gv[i];                 // row t=row, cols d = 8ch..8ch+7
      int tc = row >> 3, tb = (row & 7) << 1, xr = ch & 3;
#pragma unroll
      for (int e = 0; e < 8; ++e) {
        int d = ch * 8 + e;
        *(__bf16*)(smem + VT_O + d * 208 + ((tc ^ xr) << 4) + tb) = v8[e];
      }
    }
  }
  __syncthreads();

  // hoisted per-lane column info (invariant over row-blocks)
  int ljv[6]; bool cok[6];
#pragma unroll
  for (int j = 0; j < 6; ++j) {
    int col = j * 16 + r16;
    ljv[j] = mod29(col);
    cok[j] = col < 87;
  }

  // QK^T row-block m (16 rows x 96 cols) + in-register masked softmax -> P
  for (int m = wave; m < 6; m += 4) {
    f32x4 s[6] = {};
#pragma unroll
    for (int kk = 0; kk < 2; ++kk) {
      bf16x8 aq = *(const bf16x8*)(smem + QS_O + (m * 16 + r16) * 144 + kk * 64 + r4 * 16);
#pragma unroll
      for (int j = 0; j < 6; ++j) {
        bf16x8 kb = *(const bf16x8*)(smem + KS_O + (j * 16 + r16) * 144 + kk * 64 + r4 * 16);
        s[j] = __builtin_amdgcn_mfma_f32_16x16x32_bf16(aq, kb, s[j], 0, 0, 0);
      }
    }
#pragma unroll
    for (int rr = 0; rr < 4; ++rr) {
      int row = m * 16 + r4 * 4 + rr;
      bool rok = row < 87;
      int lr = mod29(row);
      float mxv = -1e30f;
#pragma unroll
      for (int j = 0; j < 6; ++j) {
        bool al = rok && cok[j] && (ljv[j] <= lr) && (ljv[j] + 21 >= lr);
        float sv = al ? s[j][rr] * 0.125f : -1e30f;
        s[j][rr] = sv;
        mxv = fmaxf(mxv, sv);
      }
      mxv = fmaxf(mxv, __shfl_xor(mxv, 1));
      mxv = fmaxf(mxv, __shfl_xor(mxv, 2));
      mxv = fmaxf(mxv, __shfl_xor(mxv, 4));
      mxv = fmaxf(mxv, __shfl_xor(mxv, 8));
      float sm = 0.f;
#pragma unroll
      for (int j = 0; j < 6; ++j) {
        float e = __expf(s[j][rr] - mxv);   // masked: exp(-1e30) == 0
        s[j][rr] = e;
        sm += e;
      }
      sm += __shfl_xor(sm, 1);
      sm += __shfl_xor(sm, 2);
      sm += __shfl_xor(sm, 4);
      sm += __shfl_xor(sm, 8);
      float inv = rok ? 1.f / sm : 0.f;
#pragma unroll
      for (int j = 0; j < 6; ++j)
        *(__hip_bfloat16*)(smem + PB_O + row * 208 + (j * 16 + r16) * 2) =
            __float2bfloat16(s[j][rr] * inv);
    }
  }
  __syncthreads();

  // Y = P V : A=P rows t (208B pitch), B=Vt rows d (208B pitch, chunk-XOR)
  for (int p = 0; p < 6; ++p) {
    int pair = wave + p * 4;
    int mt = pair >> 2, nt = pair & 3;
    int d = nt * 16 + r16;
    int dx = (d >> 3) & 3;
    f32x4 acc = {0.f, 0.f, 0.f, 0.f};
#pragma unroll
    for (int kk = 0; kk < 3; ++kk) {
      bf16x8 a  = *(const bf16x8*)(smem + PB_O + (mt * 16 + r16) * 208 + kk * 64 + r4 * 16);
      bf16x8 bb = *(const bf16x8*)(smem + VT_O + d * 208 + (((kk * 4 + r4) ^ dx) << 4));
      acc = __builtin_amdgcn_mfma_f32_16x16x32_bf16(a, bb, acc, 0, 0, 0);
    }
    int t0 = mt * 16 + r4 * 4;
#pragma unroll
    for (int r = 0; r < 4; ++r) {
      int t = t0 + r;
      if (t < 87)
        y_ws[((size_t)b * 87 + t) * 512 + h * 64 + d] = __float2bfloat16(acc[r]);
    }
  }
}

// ---------------- launch ----------------
extern "C" void kernel_launch(void* const* d_in, const int* in_sizes, int n_in,
                              void* d_out, int out_size, void* d_ws, size_t ws_size,
                              hipStream_t stream) {
  const float* x  = (const float*)d_in[0];
  const float* Wq = (const float*)d_in[1];
  const float* bq = (const float*)d_in[2];
  const float* Wk = (const float*)d_in[3];
  const float* bk = (const float*)d_in[4];
  const float* Wv = (const float*)d_in[5];
  const float* bv = (const float*)d_in[6];
  const float* Wp = (const float*)d_in[7];
  const float* bp = (const float*)d_in[8];
  float* out = (float*)d_out;

  char* ws = (char*)d_ws;
  size_t off = 0;
  __hip_bfloat16* xb    = (__hip_bfloat16*)(ws + off); off += (size_t)BT_ * 512 * 2;
  __hip_bfloat16* wqkv  = (__hip_bfloat16*)(ws + off); off += 1536 * 512 * 2;
  __hip_bfloat16* wp    = (__hip_bfloat16*)(ws + off); off += 512 * 512 * 2;
  float*          biasc = (float*)(ws + off);          off += 8192;
  __hip_bfloat16* q_ws  = (__hip_bfloat16*)(ws + off); off += (size_t)BH_ * 6144 * 2;
  __hip_bfloat16* k_ws  = (__hip_bfloat16*)(ws + off); off += (size_t)BH_ * 6144 * 2;
  __hip_bfloat16* v_ws  = (__hip_bfloat16*)(ws + off); off += (size_t)BH_ * 6144 * 2;
  __hip_bfloat16* yb = xb;  // alias: xb fully consumed by gemm_qkv before attn writes y

  if (ws_size < off) return;

  convert_x_kernel<<<2048, 256, 0, stream>>>(x, xb, BT_ * 512 / 4);
  convert_w_kernel<<<1024, 256, 0, stream>>>(Wq, Wk, Wv, Wp, bq, bk, bv, wqkv, wp, biasc);
  // qkv: 128x128 tiles -> 348 x 12 = 4176 blocks (div by 8)
  gemmr_kernel<0><<<4176, 256, 0, stream>>>(xb, wqkv, biasc, 12, q_ws, k_ws, v_ws);
  attn_kernel<<<BH_, 256, 0, stream>>>(q_ws, k_ws, v_ws, yb);
  // proj: 128x128 tiles -> 348 x 4 = 1392 blocks (div by 8)
  gemmr_kernel<1><<<1392, 256, 0, stream>>>(yb, wp, bp, 4, out, nullptr, nullptr);
}